// Round 1
// baseline (34003.174 us; speedup 1.0000x reference)
//
#include <hip/hip_runtime.h>
#include <hip/hip_bf16.h>

// SDEBlock3D: 20 Euler-Maruyama steps of
//   y += (conv3d(16->64,3^3) -> tanh -> conv3d(64->16,3^3))(y) * dt + sigma*sqrt(dt)*z
// Layout: y fp32 [16][64][64][64] (lives in d_out), h bf16 [64][64^3] in d_ws.

#define S    64
#define SS   4096      // 64*64
#define SSS  262144    // 64^3
#define DIMC 16
#define HIDC 64
#define DT_F 0.05f
#define SIG_SDT 0.022360679774997897f  // 0.1 * sqrt(0.05)

// ---------------------------------------------------------------------------
// conv1 + tanh: y[16][S^3] fp32 -> h[64][S^3] bf16
// Block: 256 thr = 16x16 spatial tile, 8-z slab, 16 out-channels.
// Grid: dim3(16, 8, 4) = 512 blocks.
// LDS: sliding 3-plane window, [slot][ic][18][18] fp32 = 62.2 KB.
// Weights read via uniform indices -> scalar loads (SGPR operand in FMA).
// ---------------------------------------------------------------------------
__global__ __launch_bounds__(256, 2)
void conv1_tanh(const float* __restrict__ y, const float* __restrict__ w1,
                const float* __restrict__ b1, __hip_bfloat16* __restrict__ h)
{
    __shared__ float tile[3][DIMC][18][18];
    const int t   = threadIdx.x;
    const int ltx = t & 15, lty = t >> 4;
    const int tx0 = (blockIdx.x & 3) << 4;
    const int ty0 = (blockIdx.x >> 2) << 4;
    const int z0  = blockIdx.y << 3;   // 8-z slab
    const int oc0 = blockIdx.z << 4;   // 16 out channels per block

    auto load_plane = [&](int gz) {
        const int sl = ((gz % 3) + 3) % 3;
        for (int i = t; i < DIMC * 324; i += 256) {
            int ic = i / 324;
            int r  = (i - ic * 324) / 18;
            int c  = i - ic * 324 - r * 18;
            int gy = ty0 + r - 1, gx = tx0 + c - 1;
            float v = 0.f;
            if ((unsigned)gz < S && (unsigned)gy < S && (unsigned)gx < S)
                v = y[(size_t)ic * SSS + (size_t)gz * SS + gy * S + gx];
            tile[sl][ic][r][c] = v;
        }
    };
    load_plane(z0 - 1);
    load_plane(z0);

    for (int zi = 0; zi < 8; ++zi) {
        const int z = z0 + zi;
        __syncthreads();           // protect slot (z+1)%3 (== plane z-2's slot)
        load_plane(z + 1);
        __syncthreads();

        const int slo0 = ((z - 1) % 3 + 3) % 3;
        const int slo1 = z % 3;
        const int slo2 = (z + 1) % 3;
        const int slo[3] = {slo0, slo1, slo2};

        float acc[16];
        #pragma unroll
        for (int o = 0; o < 16; ++o) acc[o] = 0.f;

        #pragma unroll 1
        for (int ic = 0; ic < DIMC; ++ic) {
            float v[27];
            #pragma unroll
            for (int dz = 0; dz < 3; ++dz) {
                const float* pp = &tile[slo[dz]][ic][lty][ltx];
                #pragma unroll
                for (int dy = 0; dy < 3; ++dy)
                    #pragma unroll
                    for (int dx = 0; dx < 3; ++dx)
                        v[dz * 9 + dy * 3 + dx] = pp[dy * 18 + dx];
            }
            // w1[oc][ic][27]; uniform index -> s_load, SGPR operand in v_fma
            const float* wr = w1 + ((size_t)oc0 * DIMC + ic) * 27;
            #pragma unroll
            for (int tap = 0; tap < 27; ++tap) {
                #pragma unroll
                for (int o = 0; o < 16; ++o)
                    acc[o] = fmaf(v[tap], wr[(size_t)o * (DIMC * 27) + tap], acc[o]);
            }
        }

        const int gy = ty0 + lty, gx = tx0 + ltx;
        const size_t base = (size_t)z * SS + gy * S + gx;
        #pragma unroll
        for (int o = 0; o < 16; ++o) {
            float r = tanhf(acc[o] + b1[oc0 + o]);
            h[(size_t)(oc0 + o) * SSS + base] = __float2bfloat16(r);
        }
    }
}

// ---------------------------------------------------------------------------
// conv2 + Euler update: h[64][S^3] bf16 -> y[16][S^3] fp32 (in place update)
// Block: 256 thr = 16x16 tile, 2-z slab, all 16 out-channels; ic chunked 4x16.
// Grid: dim3(16, 32) = 512 blocks.
// ---------------------------------------------------------------------------
__global__ __launch_bounds__(256, 2)
void conv2_update(const __hip_bfloat16* __restrict__ h, const float* __restrict__ w2,
                  const float* __restrict__ b2, float* __restrict__ y,
                  const float* __restrict__ nz)
{
    __shared__ float tile[3][16][18][18];
    const int t   = threadIdx.x;
    const int ltx = t & 15, lty = t >> 4;
    const int tx0 = (blockIdx.x & 3) << 4;
    const int ty0 = (blockIdx.x >> 2) << 4;
    const int z0  = blockIdx.y << 1;   // 2-z slab

    for (int zi = 0; zi < 2; ++zi) {
        const int z = z0 + zi;
        float acc[16];
        #pragma unroll
        for (int o = 0; o < 16; ++o) acc[o] = 0.f;

        #pragma unroll 1
        for (int ch = 0; ch < 4; ++ch) {
            const int icb = ch << 4;
            __syncthreads();
            // load 3 full planes of this 16-channel chunk (slot == dz)
            for (int i = t; i < 3 * 16 * 324; i += 256) {
                int sl  = i / 5184;
                int rem = i - sl * 5184;
                int ic  = rem / 324;
                int r   = (rem - ic * 324) / 18;
                int c   = rem - ic * 324 - r * 18;
                int gz  = z - 1 + sl;
                int gy  = ty0 + r - 1, gx = tx0 + c - 1;
                float v = 0.f;
                if ((unsigned)gz < S && (unsigned)gy < S && (unsigned)gx < S)
                    v = __bfloat162float(
                        h[(size_t)(icb + ic) * SSS + (size_t)gz * SS + gy * S + gx]);
                tile[sl][ic][r][c] = v;
            }
            __syncthreads();

            #pragma unroll 1
            for (int ic = 0; ic < 16; ++ic) {
                float v[27];
                #pragma unroll
                for (int dz = 0; dz < 3; ++dz) {
                    const float* pp = &tile[dz][ic][lty][ltx];
                    #pragma unroll
                    for (int dy = 0; dy < 3; ++dy)
                        #pragma unroll
                        for (int dx = 0; dx < 3; ++dx)
                            v[dz * 9 + dy * 3 + dx] = pp[dy * 18 + dx];
                }
                // w2[oc][ic(64)][27]
                const float* wr = w2 + (size_t)(icb + ic) * 27;
                #pragma unroll
                for (int tap = 0; tap < 27; ++tap) {
                    #pragma unroll
                    for (int o = 0; o < 16; ++o)
                        acc[o] = fmaf(v[tap], wr[(size_t)o * (HIDC * 27) + tap], acc[o]);
                }
            }
        }

        const int gy = ty0 + lty, gx = tx0 + ltx;
        const size_t base = (size_t)z * SS + gy * S + gx;
        #pragma unroll
        for (int o = 0; o < 16; ++o) {
            const size_t idx = (size_t)o * SSS + base;
            const float f = acc[o] + b2[o];
            y[idx] = y[idx] + f * DT_F + SIG_SDT * nz[idx];
        }
    }
}

// ---------------------------------------------------------------------------
extern "C" void kernel_launch(void* const* d_in, const int* in_sizes, int n_in,
                              void* d_out, int out_size, void* d_ws, size_t ws_size,
                              hipStream_t stream)
{
    const float* x     = (const float*)d_in[0];
    // d_in[1] = integration_time, unused (ts=[0,1], dt=0.05, 20 steps fixed)
    const float* w1    = (const float*)d_in[2];
    const float* b1    = (const float*)d_in[3];
    const float* w2    = (const float*)d_in[4];
    const float* b2    = (const float*)d_in[5];
    const float* noise = (const float*)d_in[6];

    float* yv = (float*)d_out;                  // state lives in d_out
    __hip_bfloat16* h = (__hip_bfloat16*)d_ws;  // 64*S^3 bf16 = 33.5 MB

    hipMemcpyAsync(yv, x, (size_t)DIMC * SSS * sizeof(float),
                   hipMemcpyDeviceToDevice, stream);

    for (int step = 0; step < 20; ++step) {
        conv1_tanh<<<dim3(16, 8, 4), 256, 0, stream>>>(yv, w1, b1, h);
        conv2_update<<<dim3(16, 32), 256, 0, stream>>>(
            h, w2, b2, yv, noise + (size_t)step * DIMC * SSS);
    }
}

// Round 2
// 2147.992 us; speedup vs baseline: 15.8302x; 15.8302x over previous
//
#include <hip/hip_runtime.h>
#include <hip/hip_bf16.h>

// SDEBlock3D via implicit-GEMM MFMA (bf16), 20 Euler-Maruyama steps.
//   y fp32 [16][64^3] channel-major lives in d_out (master state).
//   yb bf16 [64^3][16] channels-last (conv1 input), in d_ws.
//   h  bf16 [64^3][64] channels-last (conv2 input), in d_ws.
//   w1t/w2t: weights pre-packed into MFMA A-fragment order (bf16), in d_ws.

#define S    64
#define SS   4096
#define SSS  262144
#define DT_F 0.05f
#define SIG_SDT 0.022360679774997897f  // 0.1*sqrt(0.05)

typedef __bf16 bf16x8 __attribute__((ext_vector_type(8)));
typedef float  f32x4  __attribute__((ext_vector_type(4)));
typedef float  f32x16 __attribute__((ext_vector_type(16)));

union B8U { uint4 u; bf16x8 b; };
__device__ inline bf16x8 as_bf16x8(uint4 u) { B8U x; x.u = u; return x.b; }

__device__ inline unsigned short bf16_bits(float f) {
    union { float f; unsigned u; } c; c.f = f;
    unsigned r = c.u + 0x7fffu + ((c.u >> 16) & 1u);   // RNE
    return (unsigned short)(r >> 16);
}

__device__ inline float tanh_fast(float v) {
    float a = fminf(fmaxf(v, -15.f), 15.f);
    float e = __expf(2.f * a);
    return (e - 1.f) * __builtin_amdgcn_rcpf(e + 1.f);
}

// ---------------------------------------------------------------------------
// Weight prep: pack w1/w2 (fp32, [oc][ic][27]) into MFMA A-fragment order bf16.
// w1t: frag(tap, mtile): lane l elem j -> A[m=mt*32+(l&31)][k=(l>>5)*8+j]
// w2t: frag(tap, kc)   : lane l elem j -> A[m=l&15][k=(l>>4)*8+j], ic=kc*32+k
// ---------------------------------------------------------------------------
__global__ void prep_weights(const float* __restrict__ w1, const float* __restrict__ w2,
                             unsigned short* __restrict__ w1t, unsigned short* __restrict__ w2t)
{
    const int t = blockIdx.x * 256 + threadIdx.x;
    if (t >= 27 * 2 * 64 * 8) return;
    const int j = t & 7, l = (t >> 3) & 63, half = (t >> 9) & 1, tap = t >> 10;
    {
        const int oc = half * 32 + (l & 31), ic = (l >> 5) * 8 + j;
        w1t[t] = bf16_bits(w1[(oc * 16 + ic) * 27 + tap]);
    }
    {
        const int oc = l & 15, ic = half * 32 + (l >> 4) * 8 + j;
        w2t[t] = bf16_bits(w2[(oc * 64 + ic) * 27 + tap]);
    }
}

// x fp32 [16][S^3] -> yb bf16 [S^3][16]
__global__ void pack_x(const float* __restrict__ x, uint4* __restrict__ yb)
{
    const int p = blockIdx.x * 256 + threadIdx.x;
    union { unsigned short s[16]; uint4 v[2]; } pk;
    #pragma unroll
    for (int c = 0; c < 16; ++c) pk.s[c] = bf16_bits(x[c * SSS + p]);
    yb[p * 2]     = pk.v[0];
    yb[p * 2 + 1] = pk.v[1];
}

// ---------------------------------------------------------------------------
// conv1: yb [p][16] bf16 -> h [p][64] bf16, 32x32x16 MFMA, fused bias+tanh.
// Block 256 thr = 4 waves: wave = (mtile = w>>1, xg = w&1). Fixed y, z-loop 4.
// LDS tile: 3 z-slots x 3 y-rows x 66 px x 2 chunks(16B) = 19008 B, no swizzle
// (px-stride = 8 dwords is already bank-balanced for the frag read pattern).
// Grid dim3(16, 64).
// ---------------------------------------------------------------------------
__device__ inline void stage1(const uint4* __restrict__ yb, uint4* tile,
                              int y, int zp, int t)
{
    uint4* dst = tile + ((zp % 3 + 3) % 3) * 396;
    for (int idx = t; idx < 396; idx += 256) {
        const int r = idx / 132, rem = idx - r * 132;
        const int px = rem >> 1;
        const int gy = y + r - 1, gx = px - 1;
        uint4 v = {0, 0, 0, 0};
        if ((unsigned)zp < 64u && (unsigned)gy < 64u && (unsigned)gx < 64u)
            v = yb[(((size_t)zp * SS + gy * S + gx) << 1) + (rem & 1)];
        dst[idx] = v;
    }
}

__global__ __launch_bounds__(256, 2)
void conv1_mfma(const uint4* __restrict__ yb, const uint4* __restrict__ w1t,
                const float* __restrict__ b1, unsigned short* __restrict__ h)
{
    __shared__ uint4 tile[3 * 396];
    const int t = threadIdx.x, lane = t & 63, w = t >> 6;
    const int mt = w >> 1, xg = w & 1;
    const int y = blockIdx.y, z0 = blockIdx.x * 4;

    bf16x8 A[27];
    #pragma unroll
    for (int tap = 0; tap < 27; ++tap)
        A[tap] = as_bf16x8(w1t[(tap * 2 + mt) * 64 + lane]);

    const int n = lane & 31, hh = lane >> 5;
    float bias[16];
    #pragma unroll
    for (int q = 0; q < 4; ++q)
        #pragma unroll
        for (int i = 0; i < 4; ++i)
            bias[q * 4 + i] = b1[mt * 32 + q * 8 + hh * 4 + i];

    stage1(yb, tile, y, z0 - 1, t);
    stage1(yb, tile, y, z0,     t);

    for (int zi = 0; zi < 4; ++zi) {
        const int z = z0 + zi;
        __syncthreads();
        stage1(yb, tile, y, z + 1, t);
        __syncthreads();

        f32x16 acc;
        #pragma unroll
        for (int i = 0; i < 16; ++i) acc[i] = 0.f;

        #pragma unroll
        for (int dz = 0; dz < 3; ++dz) {
            const uint4* pl = tile + (((z - 1 + dz) % 3 + 3) % 3) * 396;
            #pragma unroll
            for (int dy = 0; dy < 3; ++dy) {
                const uint4* row = pl + dy * 132;
                #pragma unroll
                for (int dx = 0; dx < 3; ++dx) {
                    bf16x8 B = as_bf16x8(row[(xg * 32 + n + dx) * 2 + hh]);
                    acc = __builtin_amdgcn_mfma_f32_32x32x16_bf16(
                              A[dz * 9 + dy * 3 + dx], B, acc, 0, 0, 0);
                }
            }
        }

        // D layout 32x32: col = lane&31 (=px), row = (reg&3)+8*(reg>>2)+4*(lane>>5)
        const int x = xg * 32 + n;
        const size_t p = (size_t)z * SS + y * S + x;
        unsigned short* hp = h + p * 64;
        #pragma unroll
        for (int q = 0; q < 4; ++q) {
            const int oc = mt * 32 + q * 8 + hh * 4;
            union { unsigned short s[4]; uint2 v; } pk;
            #pragma unroll
            for (int i = 0; i < 4; ++i)
                pk.s[i] = bf16_bits(tanh_fast(acc[q * 4 + i] + bias[q * 4 + i]));
            *(uint2*)(hp + oc) = pk.v;
        }
    }
}

// ---------------------------------------------------------------------------
// conv2: h [p][64] bf16 -> Euler update of y fp32 + yb bf16, 16x16x32 MFMA.
// Block 256 thr = 4 waves: wave = (kc = w>>1 (ic-half), xg = w&1 (16-px group)).
// Fixed y, x-half (32 px), z-loop 8. Partial sums over kc reduced via LDS.
// LDS tile 3 z-slots x 3 rows x 34 px x 8 chunks, XOR-swizzled (c ^ (px&7))
// so ds_write_b128 staging and ds_read_b128 frag reads are bank-balanced.
// Grid dim3(2, 64, 8).
// ---------------------------------------------------------------------------
__device__ inline void stage2(const uint4* __restrict__ hsrc, uint4* tile,
                              int y, int x0, int zp, int t)
{
    uint4* dst = tile + ((zp % 3 + 3) % 3) * 816;
    for (int idx = t; idx < 816; idx += 256) {
        const int r = idx / 272, rem = idx - r * 272;
        const int px = rem >> 3, c = rem & 7;
        const int gy = y + r - 1, gx = x0 + px - 1;
        uint4 v = {0, 0, 0, 0};
        if ((unsigned)zp < 64u && (unsigned)gy < 64u && (unsigned)gx < 64u)
            v = hsrc[((size_t)zp * SS + gy * S + gx) * 8 + c];
        dst[r * 272 + px * 8 + (c ^ (px & 7))] = v;
    }
}

__global__ __launch_bounds__(256, 3)
void conv2_mfma(const uint4* __restrict__ hsrc, const uint4* __restrict__ w2t,
                const float* __restrict__ b2, const float* __restrict__ ysrc,
                float* __restrict__ ydst, unsigned short* __restrict__ yb,
                const float* __restrict__ nz)
{
    __shared__ uint4 tile[3 * 816];
    __shared__ f32x4 scratch[128];
    const int t = threadIdx.x, lane = t & 63, w = t >> 6;
    const int kc = w >> 1, xg = w & 1;
    const int x0 = blockIdx.x * 32, y = blockIdx.y, z0 = blockIdx.z * 8;

    bf16x8 A[27];
    #pragma unroll
    for (int tap = 0; tap < 27; ++tap)
        A[tap] = as_bf16x8(w2t[(tap * 2 + kc) * 64 + lane]);

    const int n16 = lane & 15, g = lane >> 4;
    float b2v[4];
    #pragma unroll
    for (int i = 0; i < 4; ++i) b2v[i] = b2[g * 4 + i];

    stage2(hsrc, tile, y, x0, z0 - 1, t);
    stage2(hsrc, tile, y, x0, z0,     t);

    for (int zi = 0; zi < 8; ++zi) {
        const int z = z0 + zi;
        __syncthreads();
        stage2(hsrc, tile, y, x0, z + 1, t);
        __syncthreads();

        f32x4 acc = {0.f, 0.f, 0.f, 0.f};
        #pragma unroll
        for (int dz = 0; dz < 3; ++dz) {
            const uint4* pl = tile + (((z - 1 + dz) % 3 + 3) % 3) * 816;
            #pragma unroll
            for (int dy = 0; dy < 3; ++dy) {
                const uint4* row = pl + dy * 272;
                #pragma unroll
                for (int dx = 0; dx < 3; ++dx) {
                    const int px = xg * 16 + n16 + dx;
                    const int c  = kc * 4 + g;
                    bf16x8 B = as_bf16x8(row[px * 8 + (c ^ (px & 7))]);
                    acc = __builtin_amdgcn_mfma_f32_16x16x32_bf16(
                              A[dz * 9 + dy * 3 + dx], B, acc, 0, 0, 0);
                }
            }
        }

        if (kc == 1) scratch[xg * 64 + lane] = acc;
        __syncthreads();
        if (kc == 0) {
            f32x4 o = scratch[xg * 64 + lane];
            // D layout 16x16: col = lane&15 (=px), row = (lane>>4)*4 + reg (=oc)
            const int x = x0 + xg * 16 + n16;
            const size_t p = (size_t)z * SS + y * S + x;
            union { unsigned short s[4]; uint2 v; } pk;
            #pragma unroll
            for (int i = 0; i < 4; ++i) {
                const size_t idx = (size_t)(g * 4 + i) * SSS + p;
                const float f  = acc[i] + o[i] + b2v[i];
                const float yv = ysrc[idx] + f * DT_F + SIG_SDT * nz[idx];
                ydst[idx] = yv;
                pk.s[i] = bf16_bits(yv);
            }
            *(uint2*)(yb + p * 16 + g * 4) = pk.v;
        }
    }
}

// ---------------------------------------------------------------------------
extern "C" void kernel_launch(void* const* d_in, const int* in_sizes, int n_in,
                              void* d_out, int out_size, void* d_ws, size_t ws_size,
                              hipStream_t stream)
{
    (void)in_sizes; (void)n_in; (void)out_size; (void)ws_size;
    const float* x     = (const float*)d_in[0];
    // d_in[1] = integration_time (unused; dt=0.05, 20 steps fixed)
    const float* w1    = (const float*)d_in[2];
    const float* b1    = (const float*)d_in[3];
    const float* w2    = (const float*)d_in[4];
    const float* b2    = (const float*)d_in[5];
    const float* noise = (const float*)d_in[6];

    char* ws = (char*)d_ws;
    unsigned short* w1t = (unsigned short*)ws;              // 55296 B
    unsigned short* w2t = (unsigned short*)(ws + 55296);    // 55296 B
    uint4* yb = (uint4*)(ws + 131072);                      // 8 MB  (bf16 [p][16])
    uint4* hb = (uint4*)(ws + 131072 + 8388608);            // 33.5 MB (bf16 [p][64])
    float* y  = (float*)d_out;

    prep_weights<<<108, 256, 0, stream>>>(w1, w2, w1t, w2t);
    pack_x<<<1024, 256, 0, stream>>>(x, yb);

    for (int s = 0; s < 20; ++s) {
        conv1_mfma<<<dim3(16, 64), 256, 0, stream>>>(
            yb, (const uint4*)w1t, b1, (unsigned short*)hb);
        const float* ys = (s == 0) ? x : (const float*)y;
        conv2_mfma<<<dim3(2, 64, 8), 256, 0, stream>>>(
            hb, (const uint4*)w2t, b2, ys, y, (unsigned short*)yb,
            noise + (size_t)s * (16 * SSS));
    }
}